// Round 4
// baseline (19194.618 us; speedup 1.0000x reference)
//
#include <hip/hip_runtime.h>
#include <hip/hip_bf16.h>

// LSTM encoder: B=64, L=2048, D=256, 4D=1024, VOCAB=6000
// R4 design: ZERO cross-WG communication in the scan.
//   prep_w : emb->bf16, W^T/U^T frag layouts (trivial).
//   xg_kernel: xg[b,t,:] = x@W precomputed for ALL t in parallel (MFMA),
//              stored bf16 in per-lane layout (bias added later in f32).
//   scan_kernel: 4 WGs x 1024 threads (16 waves) — one WG per 16-row group.
//              U (512KB/group) lives in VGPRs: 128 regs/lane across 16 waves.
//              Wave w owns d-channels [16w,16w+16) x all 4 gates, so gates
//              stay in the wave's own accumulators (no gate exchange).
//              h(t) goes through LDS (double-buffered, 528B row stride for
//              bank spread); ONE raw s_barrier per step. c,h state in regs.

#define B_     64
#define L_     2048
#define D_     256
#define G4_    1024
#define VOCAB_ 6000

typedef short    s16x8 __attribute__((ext_vector_type(8)));
typedef float    f32x4 __attribute__((ext_vector_type(4)));
typedef unsigned u32x2 __attribute__((ext_vector_type(2)));
typedef unsigned u32x4 __attribute__((ext_vector_type(4)));

// ---- ws layout (bytes) ----
#define OFF_EMBB   0u            // VOCAB*D bf16 = 3,072,000
#define OFF_WT     3072000u      // 4D x D bf16 (W^T) = 524,288
#define OFF_UT     3596288u      // 4D x D bf16 (U^T) = 524,288
#define OFF_XG     4120576u      // L*4*16*64*32 B = 268,435,456 (bf16 lane layout)
#define WS_NEED    272556032u

__global__ void prep_kernel(const float* __restrict__ emb,
                            const float* __restrict__ W,
                            const float* __restrict__ U,
                            __hip_bfloat16* __restrict__ embb,
                            __hip_bfloat16* __restrict__ Wt,
                            __hip_bfloat16* __restrict__ Ut) {
  const int stride = gridDim.x * blockDim.x;
  const int i0 = blockIdx.x * blockDim.x + threadIdx.x;
  for (int i = i0; i < VOCAB_ * D_; i += stride)
    embb[i] = __float2bfloat16(emb[i]);
  for (int i = i0; i < D_ * G4_; i += stride) {
    int k = i >> 10;            // row in W/U (0..255)
    int n = i & (G4_ - 1);      // col (0..1023)
    Wt[n * D_ + k] = __float2bfloat16(W[i]);
    Ut[n * D_ + k] = __float2bfloat16(U[i]);
  }
}

__device__ inline unsigned pk2(float a, float b) {
  return (unsigned)__bfloat16_as_ushort(__float2bfloat16(a)) |
         ((unsigned)__bfloat16_as_ushort(__float2bfloat16(b)) << 16);
}
__device__ inline float bl(unsigned u) {
  union { unsigned u; float f; } c; c.u = u << 16; return c.f;
}
__device__ inline float bh(unsigned u) {
  union { unsigned u; float f; } c; c.u = u & 0xffff0000u; return c.f;
}
__device__ inline float fsigmoid(float x) { return 1.f / (1.f + __expf(-x)); }
__device__ inline float ftanh(float x)    { return 1.f - 2.f / (__expf(2.f * x) + 1.f); }

// ---- xg precompute: grid 512 = 32 t-chunks x 4 groups x 4 gate-quarters ----
// WG (tc,g,Q): 64 timesteps, rows g*16..+16, cols Q*256..+256.
// Wave wv owns cols Q*256 + wv*64 + nt*16 + (l&15), nt=0..3.
__global__ __launch_bounds__(256, 2)
void xg_kernel(const int* __restrict__ ctx,
               const __hip_bfloat16* __restrict__ embb,
               const __hip_bfloat16* __restrict__ Wt,
               char* __restrict__ xg) {
  const int bid = blockIdx.x;
  const int Q   = bid & 3;
  const int g   = (bid >> 2) & 3;
  const int tc  = bid >> 4;            // 0..31
  const int tid = threadIdx.x;
  const int wv  = tid >> 6;
  const int l   = tid & 63;
  const int l15 = l & 15, lhi = l >> 4;
  const int row0 = g * 16;

  // B-frags: bfr[kk][nt], k = kk*32 + lhi*8 + j
  s16x8 bfr[8][4];
#pragma unroll
  for (int nt = 0; nt < 4; ++nt) {
    const int n = Q * 256 + wv * 64 + nt * 16 + l15;
    const __hip_bfloat16* wp = Wt + n * D_ + lhi * 8;
#pragma unroll
    for (int kk = 0; kk < 8; ++kk)
      bfr[kk][nt] = *(const s16x8*)(wp + kk * 32);
  }

  for (int tt = 0; tt < 64; ++tt) {
    const int t = tc * 64 + tt;
    const int tok = ctx[(row0 + l15) * L_ + t];
    const __hip_bfloat16* xp = embb + tok * D_ + lhi * 8;
    s16x8 af[8];
#pragma unroll
    for (int kk = 0; kk < 8; ++kk)
      af[kk] = *(const s16x8*)(xp + kk * 32);

    f32x4 acc[4];
#pragma unroll
    for (int nt = 0; nt < 4; ++nt) acc[nt] = (f32x4){0.f, 0.f, 0.f, 0.f};
#pragma unroll
    for (int kk = 0; kk < 8; ++kk) {
#pragma unroll
      for (int nt = 0; nt < 4; ++nt)
        acc[nt] = __builtin_amdgcn_mfma_f32_16x16x32_bf16(af[kk], bfr[kk][nt], acc[nt], 0, 0, 0);
    }

    // store per-lane layout: scan-wave w_scan = wv*4+nt, scan-lane == l,
    // byte = ((((t*4+g)*16 + w_scan)*64 + l)*32 + Q*8 + r*2
#pragma unroll
    for (int nt = 0; nt < 4; ++nt) {
      u32x2 v;
      v.x = pk2(acc[nt][0], acc[nt][1]);
      v.y = pk2(acc[nt][2], acc[nt][3]);
      char* p = xg + (size_t)((((t * 4 + g) * 16 + wv * 4 + nt) * 64 + l) * 32 + Q * 8);
      *(u32x2*)p = v;
    }
  }
}

// ---- scan: 4 WGs x 1024 threads, no cross-WG traffic ----
__global__ __launch_bounds__(1024, 4)
void scan_kernel(const int* __restrict__ ctx,
                 const float* __restrict__ bias,
                 const __hip_bfloat16* __restrict__ Ut,
                 const char* __restrict__ xg,
                 float* __restrict__ out) {
  const int g   = blockIdx.x;          // row group
  const int tid = threadIdx.x;
  const int w   = tid >> 6;            // wave 0..15: owns d in [w*16, w*16+16)
  const int l   = tid & 63;
  const int l15 = l & 15, lhi = l >> 4;
  const int row0 = g * 16;

  // h double-buffer: 16 rows x 264 bf16 (528B stride: banks rotate 4/row)
  __shared__ unsigned short hbufs[2][16][264];

  // bias per lane: gate q, d = w*16 + l15
  float bq[4];
#pragma unroll
  for (int q = 0; q < 4; ++q) bq[q] = bias[q * D_ + w * 16 + l15];

  // U B-frags: bfr[kk][q], col n = q*256 + w*16 + l15
  s16x8 bfr[8][4];
#pragma unroll
  for (int q = 0; q < 4; ++q) {
    const int n = q * D_ + w * 16 + l15;
    const __hip_bfloat16* up = Ut + n * D_ + lhi * 8;
#pragma unroll
    for (int kk = 0; kk < 8; ++kk)
      bfr[kk][q] = *(const s16x8*)(up + kk * 32);
  }

  // zero both h buffers (h(-1) = 0)
  for (int i = tid; i < 2 * 16 * 264; i += 1024)
    ((unsigned short*)hbufs)[i] = 0;
  __syncthreads();

  // state: rows lhi*4+r, d = w*16+l15
  float c[4]  = {0.f, 0.f, 0.f, 0.f};
  float hp[4] = {0.f, 0.f, 0.f, 0.f};

  // xg per-lane stream: 32B/step
  const char* xgl = xg + (size_t)(((g * 16 + w) * 64 + l) * 32);
  const size_t xstep = 4 * 16 * 64 * 32;   // 131072 B per t
  u32x4 xga = *(const u32x4*)(xgl);
  u32x4 xgb = *(const u32x4*)(xgl + 16);

  int tk[4];
#pragma unroll
  for (int r = 0; r < 4; ++r) tk[r] = ctx[(row0 + lhi * 4 + r) * L_];

  for (int t = 0; t < L_; ++t) {
    // ---- prefetch next xg + tokens (no dependence, hidden under MFMA)
    u32x4 nxa = xga, nxb = xgb;
    int ntk0 = tk[0], ntk1 = tk[1], ntk2 = tk[2], ntk3 = tk[3];
    if (t + 1 < L_) {
      const char* np = xgl + (size_t)(t + 1) * xstep;
      nxa = *(const u32x4*)(np);
      nxb = *(const u32x4*)(np + 16);
      ntk0 = ctx[(row0 + lhi * 4 + 0) * L_ + t + 1];
      ntk1 = ctx[(row0 + lhi * 4 + 1) * L_ + t + 1];
      ntk2 = ctx[(row0 + lhi * 4 + 2) * L_ + t + 1];
      ntk3 = ctx[(row0 + lhi * 4 + 3) * L_ + t + 1];
    }

    // ---- acc init = bias + xg (f32)
    f32x4 acc0, acc1, acc2, acc3;
    acc0[0] = bq[0] + bl(xga.x); acc0[1] = bq[0] + bh(xga.x);
    acc0[2] = bq[0] + bl(xga.y); acc0[3] = bq[0] + bh(xga.y);
    acc1[0] = bq[1] + bl(xga.z); acc1[1] = bq[1] + bh(xga.z);
    acc1[2] = bq[1] + bl(xga.w); acc1[3] = bq[1] + bh(xga.w);
    acc2[0] = bq[2] + bl(xgb.x); acc2[1] = bq[2] + bh(xgb.x);
    acc2[2] = bq[2] + bl(xgb.y); acc2[3] = bq[2] + bh(xgb.y);
    acc3[0] = bq[3] + bl(xgb.z); acc3[1] = bq[3] + bh(xgb.z);
    acc3[2] = bq[3] + bl(xgb.w); acc3[3] = bq[3] + bh(xgb.w);

    // ---- h(t-1) A-frags from LDS buf[t&1]: lane row l15, k = kk*32+lhi*8+j
    const char* hb = (const char*)(&hbufs[t & 1][0][0]) + l15 * 528 + lhi * 16;
    s16x8 hf[8];
#pragma unroll
    for (int kk = 0; kk < 8; ++kk)
      hf[kk] = *(const s16x8*)(hb + kk * 64);

    // ---- 32 MFMAs: h @ U for this wave's 64 cols (4 gates x 16 d)
#pragma unroll
    for (int kk = 0; kk < 8; ++kk) {
      acc0 = __builtin_amdgcn_mfma_f32_16x16x32_bf16(hf[kk], bfr[kk][0], acc0, 0, 0, 0);
      acc1 = __builtin_amdgcn_mfma_f32_16x16x32_bf16(hf[kk], bfr[kk][1], acc1, 0, 0, 0);
      acc2 = __builtin_amdgcn_mfma_f32_16x16x32_bf16(hf[kk], bfr[kk][2], acc2, 0, 0, 0);
      acc3 = __builtin_amdgcn_mfma_f32_16x16x32_bf16(hf[kk], bfr[kk][3], acc3, 0, 0, 0);
    }

    // ---- elementwise LSTM (4 rows x 1 d per lane), state in regs
    float* ob = out + ((size_t)(row0 + lhi * 4) * L_ + t) * D_ + w * 16 + l15;
    unsigned short hw[4];
#pragma unroll
    for (int r = 0; r < 4; ++r) {
      float i_ = fsigmoid(acc0[r]);
      float f_ = fsigmoid(acc1[r]);
      float cn = f_ * c[r] + i_ * ftanh(acc2[r]);
      float o_ = fsigmoid(acc3[r]);
      float hn = o_ * ftanh(cn);
      const bool upd = (tk[r] != 0);
      c[r]  = upd ? cn : c[r];
      hp[r] = upd ? hn : hp[r];
      hw[r] = __bfloat16_as_ushort(__float2bfloat16(hp[r]));
      ob[(size_t)r * (L_ * D_)] = hp[r];   // fire-and-forget f32 output
    }

    // ---- publish h(t) to buf[(t+1)&1]
#pragma unroll
    for (int r = 0; r < 4; ++r)
      hbufs[(t + 1) & 1][lhi * 4 + r][w * 16 + l15] = hw[r];

    asm volatile("s_waitcnt lgkmcnt(0)" ::: "memory");
    __builtin_amdgcn_s_barrier();
    asm volatile("" ::: "memory");   // no LDS op may cross the barrier

    xga = nxa; xgb = nxb;
    tk[0] = ntk0; tk[1] = ntk1; tk[2] = ntk2; tk[3] = ntk3;
  }
}

extern "C" void kernel_launch(void* const* d_in, const int* in_sizes, int n_in,
                              void* d_out, int out_size, void* d_ws, size_t ws_size,
                              hipStream_t stream) {
  const int*   ctx  = (const int*)d_in[0];
  const float* emb  = (const float*)d_in[1];
  const float* W    = (const float*)d_in[2];
  const float* U    = (const float*)d_in[3];
  const float* bias = (const float*)d_in[4];
  float* out = (float*)d_out;

  char* ws = (char*)d_ws;
  __hip_bfloat16* embb = (__hip_bfloat16*)(ws + OFF_EMBB);
  __hip_bfloat16* Wt   = (__hip_bfloat16*)(ws + OFF_WT);
  __hip_bfloat16* Ut   = (__hip_bfloat16*)(ws + OFF_UT);
  char*           xgb  = ws + OFF_XG;

  // (requires ws_size >= ~273 MB; xg fully rewritten every launch, no
  //  cross-launch state, no memsets -> graph-capture safe & deterministic)
  prep_kernel<<<1024, 256, 0, stream>>>(emb, W, U, embb, Wt, Ut);
  xg_kernel<<<512, 256, 0, stream>>>(ctx, embb, Wt, xgb);
  scan_kernel<<<4, 1024, 0, stream>>>(ctx, bias, Ut, xgb, out);
}

// Round 5
// 11958.038 us; speedup vs baseline: 1.6052x; 1.6052x over previous
//
#include <hip/hip_runtime.h>
#include <hip/hip_bf16.h>

// LSTM encoder: B=64, L=2048, D=256, 4D=1024, VOCAB=6000
// R5: zero-comm scan, register-economics fixed.
//   scan: 4 WGs x 512 thr (8 waves, 2 waves/SIMD, 256-VGPR cap). Wave w owns
//   d-range [w*32,w*32+32) for all 4 gates = 8 n-strips, 64 U-frags (1KB ea).
//   U tiers per wave: 24 frags in VGPRs (kk 0-2), 16 in LDS (kk 3-4, 128KB
//   dynamic LDS), 24 streamed from L2 per step (kk 5-7, 3 pipelined bands).
//   h(t) via LDS double-buffer; ONE raw s_barrier/step; c,h state in regs;
//   gates never leave the wave's accumulators.

#define B_     64
#define L_     2048
#define D_     256
#define G4_    1024
#define VOCAB_ 6000

typedef short    s16x8 __attribute__((ext_vector_type(8)));
typedef float    f32x4 __attribute__((ext_vector_type(4)));
typedef unsigned u32x2 __attribute__((ext_vector_type(2)));
typedef unsigned u32x4 __attribute__((ext_vector_type(4)));

// ---- ws layout (bytes) ----
#define OFF_EMBB   0u            // VOCAB*D bf16 = 3,072,000
#define OFF_WT     3072000u      // [n][k] bf16 = 524,288
#define OFF_UF     3596288u      // U frag layout [w][fj][l][j] bf16 = 524,288
#define OFF_XG     4120576u      // [t][g][w][l][64B] = 268,435,456
#define WS_NEED    272556032u

#define SMEM_U     131072        // 8 waves x 16 frags x 64 lanes x 16B
#define HSTR       264           // h row stride in ushorts (256+8 pad)
#define SMEM_TOTAL (SMEM_U + 2*16*HSTR*2)   // 147,968

__global__ void prep_kernel(const float* __restrict__ emb,
                            const float* __restrict__ W,
                            const float* __restrict__ U,
                            __hip_bfloat16* __restrict__ embb,
                            __hip_bfloat16* __restrict__ Wt,
                            __hip_bfloat16* __restrict__ Ufrag) {
  const int stride = gridDim.x * blockDim.x;
  const int i0 = blockIdx.x * blockDim.x + threadIdx.x;
  for (int i = i0; i < VOCAB_ * D_; i += stride)
    embb[i] = __float2bfloat16(emb[i]);
  for (int i = i0; i < D_ * G4_; i += stride) {
    int k = i >> 10;
    int n = i & (G4_ - 1);
    Wt[n * D_ + k] = __float2bfloat16(W[i]);
  }
  // U frag layout: elem i = ((w*64 + fj)*64 + l)*8 + j
  //   fj = kk*8 + s;  s = q*2 + nt
  //   n = q*256 + w*32 + nt*16 + (l&15);  k = kk*32 + (l>>4)*8 + j
  for (int i = i0; i < 8 * 64 * 64 * 8; i += stride) {
    int j  = i & 7;
    int l  = (i >> 3) & 63;
    int fj = (i >> 9) & 63;
    int w  = (i >> 15) & 7;
    int kk = fj >> 3, s = fj & 7;
    int q = s >> 1, nt = s & 1;
    int n = q * 256 + w * 32 + nt * 16 + (l & 15);
    int k = kk * 32 + (l >> 4) * 8 + j;
    Ufrag[i] = __float2bfloat16(U[k * G4_ + n]);
  }
}

__device__ inline unsigned pk2(float a, float b) {
  return (unsigned)__bfloat16_as_ushort(__float2bfloat16(a)) |
         ((unsigned)__bfloat16_as_ushort(__float2bfloat16(b)) << 16);
}
__device__ inline float bl(unsigned u) {
  union { unsigned u; float f; } c; c.u = u << 16; return c.f;
}
__device__ inline float bh(unsigned u) {
  union { unsigned u; float f; } c; c.u = u & 0xffff0000u; return c.f;
}
__device__ inline float fsigmoid(float x) { return 1.f / (1.f + __expf(-x)); }
__device__ inline float ftanh(float x)    { return 1.f - 2.f / (__expf(2.f * x) + 1.f); }

// ---- xg precompute: grid 512 = 32 t-chunks x 4 groups x 4 gates ----
__global__ __launch_bounds__(256, 2)
void xg_kernel(const int* __restrict__ ctx,
               const __hip_bfloat16* __restrict__ embb,
               const __hip_bfloat16* __restrict__ Wt,
               char* __restrict__ xg) {
  const int bid = blockIdx.x;
  const int Q   = bid & 3;             // gate
  const int g   = (bid >> 2) & 3;      // row group
  const int tc  = bid >> 4;            // 0..31, 64 t each
  const int tid = threadIdx.x;
  const int wv  = tid >> 6;
  const int l   = tid & 63;
  const int l15 = l & 15, lhi = l >> 4;
  const int row0 = g * 16;

  s16x8 bfr[8][4];
#pragma unroll
  for (int nt = 0; nt < 4; ++nt) {
    const int n = Q * 256 + wv * 64 + nt * 16 + l15;
    const __hip_bfloat16* wp = Wt + n * D_ + lhi * 8;
#pragma unroll
    for (int kk = 0; kk < 8; ++kk)
      bfr[kk][nt] = *(const s16x8*)(wp + kk * 32);
  }

  for (int tt = 0; tt < 64; ++tt) {
    const int t = tc * 64 + tt;
    const int tok = ctx[(row0 + l15) * L_ + t];
    const __hip_bfloat16* xp = embb + tok * D_ + lhi * 8;
    s16x8 af[8];
#pragma unroll
    for (int kk = 0; kk < 8; ++kk)
      af[kk] = *(const s16x8*)(xp + kk * 32);

    f32x4 acc[4];
#pragma unroll
    for (int nt = 0; nt < 4; ++nt) acc[nt] = (f32x4){0.f, 0.f, 0.f, 0.f};
#pragma unroll
    for (int kk = 0; kk < 8; ++kk)
#pragma unroll
      for (int nt = 0; nt < 4; ++nt)
        acc[nt] = __builtin_amdgcn_mfma_f32_16x16x32_bf16(af[kk], bfr[kk][nt], acc[nt], 0, 0, 0);

    // store to scan per-lane layout: scan-wave ws = wv*2+(nt>>1), strip
    // s = Q*2+(nt&1); lane base 64B; word s*2+rr = pk2(row pair)
#pragma unroll
    for (int nt = 0; nt < 4; ++nt) {
      const int ws = wv * 2 + (nt >> 1);
      const int s  = Q * 2 + (nt & 1);
      u32x2 vv;
      vv.x = pk2(acc[nt][0], acc[nt][1]);
      vv.y = pk2(acc[nt][2], acc[nt][3]);
      char* p = xg + (size_t)(((t * 4 + g) * 8 + ws) * 64 + l) * 64 + s * 8;
      *(u32x2*)p = vv;
    }
  }
}

// ---- scan: 4 WGs x 512 threads, zero cross-WG traffic ----
__global__ __launch_bounds__(512, 2)
void scan_kernel(const int* __restrict__ ctx,
                 const float* __restrict__ bias,
                 const __hip_bfloat16* __restrict__ Ufrag,
                 const char* __restrict__ xg,
                 float* __restrict__ out) {
  extern __shared__ __align__(16) char smem[];
  s16x8*          ulds = (s16x8*)smem;
  unsigned short* hlds = (unsigned short*)(smem + SMEM_U);

  const int g   = blockIdx.x;
  const int tid = threadIdx.x;
  const int w   = tid >> 6;            // wave: d in [w*32, w*32+32)
  const int l   = tid & 63;
  const int l15 = l & 15, lhi = l >> 4;
  const int row0 = g * 16;

  const s16x8* uf = (const s16x8*)Ufrag;

  // U register tier: fj 0..23 (kk 0..2)
  s16x8 ur[24];
#pragma unroll
  for (int fj = 0; fj < 24; ++fj)
    ur[fj] = uf[(w * 64 + fj) * 64 + l];

  // U LDS tier: fj 24..39 (kk 3..4) -> slot (w*16 + fj-24)
#pragma unroll
  for (int fj = 24; fj < 40; ++fj)
    ulds[(w * 16 + (fj - 24)) * 64 + l] = uf[(w * 64 + fj) * 64 + l];

  // zero h double-buffer
  for (int i = tid; i < 2 * 16 * HSTR; i += 512) hlds[i] = 0;

  // bias per strip s = q*2+nt, d = w*32 + nt*16 + l15
  float bq[8];
#pragma unroll
  for (int s = 0; s < 8; ++s)
    bq[s] = bias[(s >> 1) * D_ + w * 32 + (s & 1) * 16 + l15];

  float c[8]  = {0.f, 0.f, 0.f, 0.f, 0.f, 0.f, 0.f, 0.f};
  float hp[8] = {0.f, 0.f, 0.f, 0.f, 0.f, 0.f, 0.f, 0.f};
  int tk[4];
#pragma unroll
  for (int r = 0; r < 4; ++r) tk[r] = ctx[(row0 + lhi * 4 + r) * L_];

  __syncthreads();

  const char* xgl = xg + ((size_t)(g * 8 + w) * 64 + l) * 64;

  for (int t = 0; t < L_; ++t) {
    // xg for THIS step (consumed at elementwise; latency hidden under MFMA)
    const u32x4* xp = (const u32x4*)(xgl + (size_t)t * 131072);
    union { u32x4 v[4]; unsigned u[16]; } xw;
    xw.v[0] = xp[0]; xw.v[1] = xp[1]; xw.v[2] = xp[2]; xw.v[3] = xp[3];

    // stream band kk=5 issued early (L2-resident, consumed in phase B)
    s16x8 sb5[8];
#pragma unroll
    for (int s = 0; s < 8; ++s) sb5[s] = uf[(w * 64 + 40 + s) * 64 + l];

    // next-step tokens
    int tkn[4];
#pragma unroll
    for (int r = 0; r < 4; ++r)
      tkn[r] = (t + 1 < L_) ? ctx[(row0 + lhi * 4 + r) * L_ + t + 1] : 0;

    // ---- phase A: h frags kk 0..3, MFMA with reg tier + LDS tier(kk3)
    const int hb = (t & 1) * (16 * HSTR);
    s16x8 hfA[4];
#pragma unroll
    for (int kk = 0; kk < 4; ++kk)
      hfA[kk] = *(const s16x8*)&hlds[hb + l15 * HSTR + kk * 32 + lhi * 8];

    f32x4 acc[8];
#pragma unroll
    for (int s = 0; s < 8; ++s) acc[s] = (f32x4){0.f, 0.f, 0.f, 0.f};

#pragma unroll
    for (int kk = 0; kk < 3; ++kk)
#pragma unroll
      for (int s = 0; s < 8; ++s)
        acc[s] = __builtin_amdgcn_mfma_f32_16x16x32_bf16(hfA[kk], ur[kk * 8 + s], acc[s], 0, 0, 0);
    {
      s16x8 ub[8];
#pragma unroll
      for (int s = 0; s < 8; ++s) ub[s] = ulds[(w * 16 + s) * 64 + l];
#pragma unroll
      for (int s = 0; s < 8; ++s)
        acc[s] = __builtin_amdgcn_mfma_f32_16x16x32_bf16(hfA[3], ub[s], acc[s], 0, 0, 0);
    }

    // ---- phase B: kk 4..7 (LDS tier kk4, stream bands kk5..7)
    s16x8 hfB[4];
#pragma unroll
    for (int kk = 0; kk < 4; ++kk)
      hfB[kk] = *(const s16x8*)&hlds[hb + l15 * HSTR + (kk + 4) * 32 + lhi * 8];
    {
      s16x8 ub[8];
#pragma unroll
      for (int s = 0; s < 8; ++s) ub[s] = ulds[(w * 16 + 8 + s) * 64 + l];
#pragma unroll
      for (int s = 0; s < 8; ++s)
        acc[s] = __builtin_amdgcn_mfma_f32_16x16x32_bf16(hfB[0], ub[s], acc[s], 0, 0, 0);
    }
    s16x8 sb6[8];
#pragma unroll
    for (int s = 0; s < 8; ++s) sb6[s] = uf[(w * 64 + 48 + s) * 64 + l];
#pragma unroll
    for (int s = 0; s < 8; ++s)
      acc[s] = __builtin_amdgcn_mfma_f32_16x16x32_bf16(hfB[1], sb5[s], acc[s], 0, 0, 0);
    s16x8 sb7[8];
#pragma unroll
    for (int s = 0; s < 8; ++s) sb7[s] = uf[(w * 64 + 56 + s) * 64 + l];
#pragma unroll
    for (int s = 0; s < 8; ++s)
      acc[s] = __builtin_amdgcn_mfma_f32_16x16x32_bf16(hfB[2], sb6[s], acc[s], 0, 0, 0);
#pragma unroll
    for (int s = 0; s < 8; ++s)
      acc[s] = __builtin_amdgcn_mfma_f32_16x16x32_bf16(hfB[3], sb7[s], acc[s], 0, 0, 0);

    // ---- elementwise: lane owns rows lhi*4+r x d = w*32+nt*16+l15
    const int nb = ((t + 1) & 1) * (16 * HSTR);
#pragma unroll
    for (int nt = 0; nt < 2; ++nt)
#pragma unroll
      for (int r = 0; r < 4; ++r) {
        const int e = nt * 4 + r;
        const int wi = nt * 2 + (r >> 1);
        const bool hi = (r & 1);
        float x0 = hi ? bh(xw.u[0 + wi]) : bl(xw.u[0 + wi]);
        float x1 = hi ? bh(xw.u[4 + wi]) : bl(xw.u[4 + wi]);
        float x2 = hi ? bh(xw.u[8 + wi]) : bl(xw.u[8 + wi]);
        float x3 = hi ? bh(xw.u[12 + wi]) : bl(xw.u[12 + wi]);
        float gi = acc[0 + nt][r] + x0 + bq[0 + nt];
        float gf = acc[2 + nt][r] + x1 + bq[2 + nt];
        float gc = acc[4 + nt][r] + x2 + bq[4 + nt];
        float go = acc[6 + nt][r] + x3 + bq[6 + nt];
        float i_ = fsigmoid(gi);
        float f_ = fsigmoid(gf);
        float o_ = fsigmoid(go);
        float cn = f_ * c[e] + i_ * ftanh(gc);
        float hn = o_ * ftanh(cn);
        const bool upd = (tk[r] != 0);
        c[e]  = upd ? cn : c[e];
        hp[e] = upd ? hn : hp[e];
        out[((size_t)(row0 + lhi * 4 + r) * L_ + t) * D_ + w * 32 + nt * 16 + l15] = hp[e];
        hlds[nb + (lhi * 4 + r) * HSTR + w * 32 + nt * 16 + l15] =
            __bfloat16_as_ushort(__float2bfloat16(hp[e]));
      }

    asm volatile("s_waitcnt lgkmcnt(0)" ::: "memory");
    __builtin_amdgcn_s_barrier();
    asm volatile("" ::: "memory");

#pragma unroll
    for (int r = 0; r < 4; ++r) tk[r] = tkn[r];
  }
}

extern "C" void kernel_launch(void* const* d_in, const int* in_sizes, int n_in,
                              void* d_out, int out_size, void* d_ws, size_t ws_size,
                              hipStream_t stream) {
  const int*   ctx  = (const int*)d_in[0];
  const float* emb  = (const float*)d_in[1];
  const float* W    = (const float*)d_in[2];
  const float* U    = (const float*)d_in[3];
  const float* bias = (const float*)d_in[4];
  float* out = (float*)d_out;

  char* ws = (char*)d_ws;
  __hip_bfloat16* embb = (__hip_bfloat16*)(ws + OFF_EMBB);
  __hip_bfloat16* Wt   = (__hip_bfloat16*)(ws + OFF_WT);
  __hip_bfloat16* Uf   = (__hip_bfloat16*)(ws + OFF_UF);
  char*           xgb  = ws + OFF_XG;

  // opt-in to >64KB dynamic LDS (host-side attr, idempotent, capture-safe)
  hipFuncSetAttribute((const void*)scan_kernel,
                      hipFuncAttributeMaxDynamicSharedMemorySize, SMEM_TOTAL);

  prep_kernel<<<1024, 256, 0, stream>>>(emb, W, U, embb, Wt, Uf);
  xg_kernel<<<512, 256, 0, stream>>>(ctx, embb, Wt, xgb);
  scan_kernel<<<4, 512, SMEM_TOTAL, stream>>>(ctx, bias, Uf, xgb, out);
}